// Round 13
// baseline (525.439 us; speedup 1.0000x reference)
//
#include <hip/hip_runtime.h>
#include <hip/hip_bf16.h>

#define BATCH 64
#define SEQ   256
#define EMB   64
#define QKVD  64
#define KD    8192      // L*EMB
#define ND    8192      // L*QKV
#define SEQD  16384     // SEQ*EMB (per-batch x row)
#define BKT   256       // k per tile: W row chunk = 1KB contiguous
#define NTK   (KD / BKT)   // 32 k-tiles

typedef __attribute__((ext_vector_type(8))) short bf16x8;
typedef __attribute__((ext_vector_type(4))) float f32x4;

struct WArgs { const float* W[6]; const float* b[6]; };

// branchless round-to-nearest-even fp32 -> bf16 bits (inputs are finite)
__device__ __forceinline__ short f2bf(float f) {
    unsigned u = __builtin_bit_cast(unsigned, f);
    u += 0x7fffu + ((u >> 16) & 1u);
    return (short)(u >> 16);
}

// async global->LDS, 16B per lane; LDS dest = wave-uniform base + lane*16
__device__ __forceinline__ void gl16(const void* g, void* l) {
    __builtin_amdgcn_global_load_lds(
        (const __attribute__((address_space(1))) void*)g,
        (__attribute__((address_space(3))) void*)l, 16, 0, 0);
}

// ---------------- kernel 1: x fp32 -> bf16 ----------------------------------
__global__ __launch_bounds__(256)
void cvt_x_kernel(const float* __restrict__ x, short* __restrict__ xb) {
    const int i = (blockIdx.x * 256 + threadIdx.x) * 4;
    float4 v = *reinterpret_cast<const float4*>(x + i);
    short4 o;
    o.x = f2bf(v.x); o.y = f2bf(v.y); o.z = f2bf(v.z); o.w = f2bf(v.w);
    *reinterpret_cast<short4*>(xb + i) = o;
}

// ---------------- kernel 2: QKV projections ---------------------------------
// C[m][n] = sum_k xs[m,k]*W[n,k] + b[n], gi in [0,6). Block 64m x 64n, 4 waves.
// ZERO s_barrier: W is wave-private (each wave stages+reads only its own 16
// rows; LDS ring-2, 1KB-contiguous issues); A (L2-resident) lives in named
// VGPRs as two 16-frag groups (no arrays -> no r10 spill), reloaded per half.
// Per-wave in-order FIFO ledger (16 issues per group/stage):
//   prologue: Agrp(0), Bgrp(0), W(0), W(1)
//   tile t:   vmcnt(32|16) [Agrp(t),W(t) landed; Bgrp(t),W(t+1) in flight]
//             half0(t); loadAgrp(t+1)
//             vmcnt(32|0)  [Bgrp(t) landed]
//             half1(t); loadBgrp(t+1); lgkm(0); stageW(t+2)  [own-slot WAR]
__global__ __launch_bounds__(256, 1)
void qkv_gemm_kernel(const short* __restrict__ xb, WArgs wa,
                     float* __restrict__ qkv) {
    __shared__ __attribute__((aligned(16))) float W_lds[2][64 * BKT]; // 128KB

    const int wv  = threadIdx.x >> 6;
    const int ln  = threadIdx.x & 63;
    const int r   = ln & 15;          // n within wave tile / A row in frag
    const int kb  = ln >> 4;          // k sub-block of 8 within 32
    const int key = r & 7;

    // bijective XCD swizzle: 768 blocks, XCD x gets logical [x*96, x*96+96)
    const int bid     = blockIdx.x;
    const int logical = (bid & 7) * 96 + (bid >> 3);
    const int gi      = logical >> 7;          // 0..5
    const int n0      = (logical & 127) * 64;  // n-tile origin
    const int g       = gi / 3;

    const char*  __restrict__ Wb8 =
        (const char*)(wa.W[gi] + (size_t)(n0 + wv * 16) * KD);
    const short* __restrict__ Ag = xb + g * KD;

    f32x4 acc0 = {0.f, 0.f, 0.f, 0.f};
    f32x4 acc1 = acc0, acc2 = acc0, acc3 = acc0;

    bf16x8 A0,A1,A2,A3,A4,A5,A6,A7,A8,A9,A10,A11,A12,A13,A14,A15;
    bf16x8 B0,B1,B2,B3,B4,B5,B6,B7,B8,B9,B10,B11,B12,B13,B14,B15;

// load one 16-frag group: substeps sb..sb+3, m-frags 0..3 (named dests)
#define LOADG(v0,v1,v2,v3,v4,v5,v6,v7,v8,v9,v10,v11,v12,v13,v14,v15, tt, sb) do { \
    const short* Ab_ = Ag + (size_t)(tt) * BKT + (sb) * 32 + kb * 8;              \
    v0  = *(const bf16x8*)(Ab_ + (size_t)( 0 + r) * SEQD +  0);                   \
    v1  = *(const bf16x8*)(Ab_ + (size_t)(16 + r) * SEQD +  0);                   \
    v2  = *(const bf16x8*)(Ab_ + (size_t)(32 + r) * SEQD +  0);                   \
    v3  = *(const bf16x8*)(Ab_ + (size_t)(48 + r) * SEQD +  0);                   \
    v4  = *(const bf16x8*)(Ab_ + (size_t)( 0 + r) * SEQD + 32);                   \
    v5  = *(const bf16x8*)(Ab_ + (size_t)(16 + r) * SEQD + 32);                   \
    v6  = *(const bf16x8*)(Ab_ + (size_t)(32 + r) * SEQD + 32);                   \
    v7  = *(const bf16x8*)(Ab_ + (size_t)(48 + r) * SEQD + 32);                   \
    v8  = *(const bf16x8*)(Ab_ + (size_t)( 0 + r) * SEQD + 64);                   \
    v9  = *(const bf16x8*)(Ab_ + (size_t)(16 + r) * SEQD + 64);                   \
    v10 = *(const bf16x8*)(Ab_ + (size_t)(32 + r) * SEQD + 64);                   \
    v11 = *(const bf16x8*)(Ab_ + (size_t)(48 + r) * SEQD + 64);                   \
    v12 = *(const bf16x8*)(Ab_ + (size_t)( 0 + r) * SEQD + 96);                   \
    v13 = *(const bf16x8*)(Ab_ + (size_t)(16 + r) * SEQD + 96);                   \
    v14 = *(const bf16x8*)(Ab_ + (size_t)(32 + r) * SEQD + 96);                   \
    v15 = *(const bf16x8*)(Ab_ + (size_t)(48 + r) * SEQD + 96);                   \
} while (0)

// one k-substep: W chunks c0,c0+1 (swizzled) -> bf16, 4 MFMAs with m-frags
#define SUB(Wrow_, cofs, m0,m1,m2,m3) do {                                        \
    const int c0_ = (cofs) + kb * 2;                                              \
    f32x4 w0_ = *(const f32x4*)((Wrow_) + ((unsigned)((c0_)     ^ key) << 2));    \
    f32x4 w1_ = *(const f32x4*)((Wrow_) + ((unsigned)((c0_ + 1) ^ key) << 2));    \
    bf16x8 bb_;                                                                   \
    bb_[0] = f2bf(w0_[0]); bb_[1] = f2bf(w0_[1]);                                 \
    bb_[2] = f2bf(w0_[2]); bb_[3] = f2bf(w0_[3]);                                 \
    bb_[4] = f2bf(w1_[0]); bb_[5] = f2bf(w1_[1]);                                 \
    bb_[6] = f2bf(w1_[2]); bb_[7] = f2bf(w1_[3]);                                 \
    acc0 = __builtin_amdgcn_mfma_f32_16x16x32_bf16(m0, bb_, acc0, 0, 0, 0);       \
    acc1 = __builtin_amdgcn_mfma_f32_16x16x32_bf16(m1, bb_, acc1, 0, 0, 0);       \
    acc2 = __builtin_amdgcn_mfma_f32_16x16x32_bf16(m2, bb_, acc2, 0, 0, 0);       \
    acc3 = __builtin_amdgcn_mfma_f32_16x16x32_bf16(m3, bb_, acc3, 0, 0, 0);       \
} while (0)

#define STAGEW(tt) do {                                                           \
    float* slot_ = &W_lds[(tt) & 1][0];                                           \
    const char* tb_ = Wb8 + (size_t)(tt) * 1024;                                  \
    _Pragma("unroll")                                                             \
    for (int i_ = 0; i_ < 16; ++i_)                                               \
        gl16(tb_ + (size_t)i_ * (KD * 4) + ((unsigned)(ln ^ (i_ & 7)) << 4),      \
             (char*)slot_ + (wv * 16 + i_) * 1024);                               \
} while (0)

    // prologue ledger: Agrp(0) x16, Bgrp(0) x16, W(0) x16, W(1) x16
    LOADG(A0,A1,A2,A3,A4,A5,A6,A7,A8,A9,A10,A11,A12,A13,A14,A15, 0, 0);
    __builtin_amdgcn_sched_barrier(0);
    LOADG(B0,B1,B2,B3,B4,B5,B6,B7,B8,B9,B10,B11,B12,B13,B14,B15, 0, 4);
    __builtin_amdgcn_sched_barrier(0);
    STAGEW(0);
    __builtin_amdgcn_sched_barrier(0);
    STAGEW(1);
    __builtin_amdgcn_sched_barrier(0);

    for (int t = 0; t < NTK; ++t) {
        // s1: need Agrp(t) + W(t). newer = Bgrp(t)?(t==0:no) + W(t+1)?
        if (t == 0 || t == NTK - 1) {
            asm volatile("s_waitcnt vmcnt(16)" ::: "memory");
        } else {
            asm volatile("s_waitcnt vmcnt(32)" ::: "memory");
        }
        __builtin_amdgcn_sched_barrier(0);
        {   // half0: k [0,128) of tile t
            const float* Wrow = &W_lds[t & 1][0] + (wv * 16 + r) * BKT;
            SUB(Wrow,  0, A0, A1, A2, A3);
            SUB(Wrow,  8, A4, A5, A6, A7);
            SUB(Wrow, 16, A8, A9, A10, A11);
            SUB(Wrow, 24, A12, A13, A14, A15);
        }
        __builtin_amdgcn_sched_barrier(0);
        if (t + 1 < NTK)
            LOADG(A0,A1,A2,A3,A4,A5,A6,A7,A8,A9,A10,A11,A12,A13,A14,A15, t + 1, 0);
        __builtin_amdgcn_sched_barrier(0);

        // s4: need Bgrp(t). newer = Agrp(t+1) + W(t+1) (both iff t+1<NTK)
        if (t + 1 < NTK) {
            asm volatile("s_waitcnt vmcnt(32)" ::: "memory");
        } else {
            asm volatile("s_waitcnt vmcnt(0)" ::: "memory");
        }
        __builtin_amdgcn_sched_barrier(0);
        {   // half1: k [128,256) of tile t
            const float* Wrow = &W_lds[t & 1][0] + (wv * 16 + r) * BKT;
            SUB(Wrow, 32, B0, B1, B2, B3);
            SUB(Wrow, 40, B4, B5, B6, B7);
            SUB(Wrow, 48, B8, B9, B10, B11);
            SUB(Wrow, 56, B12, B13, B14, B15);
        }
        __builtin_amdgcn_sched_barrier(0);
        if (t + 1 < NTK)
            LOADG(B0,B1,B2,B3,B4,B5,B6,B7,B8,B9,B10,B11,B12,B13,B14,B15, t + 1, 4);
        __builtin_amdgcn_sched_barrier(0);
        if (t + 2 < NTK) {
            asm volatile("s_waitcnt lgkmcnt(0)" ::: "memory"); // own W reads done
            STAGEW(t + 2);   // wave-private slot t&1: safe, no barrier
        }
        __builtin_amdgcn_sched_barrier(0);
    }

    // D layout (m89): col = lane&15, row = (lane>>4)*4 + reg
    const int nbr = n0 + wv * 16 + r;
    const float bias = wa.b[gi][nbr];
    float* orow = qkv + (size_t)gi * (BATCH * ND) + nbr;
    #pragma unroll
    for (int reg = 0; reg < 4; ++reg) {
        const int m = kb * 4 + reg;
        orow[(size_t)(m)      * ND] = acc0[reg] + bias;
        orow[(size_t)(m + 16) * ND] = acc1[reg] + bias;
        orow[(size_t)(m + 32) * ND] = acc2[reg] + bias;
        orow[(size_t)(m + 48) * ND] = acc3[reg] + bias;
    }
#undef LOADG
#undef SUB
#undef STAGEW
}

// ---------------- kernel 3: attention per (batch, group) -------------------
// scores[i][j] = Q[i,:]·K[j,:]; softmax over i (query axis); Z = attn·V; ×0.125
__global__ __launch_bounds__(256)
void attn_kernel(const float* __restrict__ qkv, float* __restrict__ out) {
    __shared__ float Ql[128 * 65];   // Q, then reused for V
    __shared__ float Kl[128 * 65];
    __shared__ float Sc[128 * 129];
    __shared__ float Pm[256];
    __shared__ float Ps[256];
    __shared__ float Rden[128];

    const int b = blockIdx.x;
    const int g = blockIdx.y;
    const int t = threadIdx.x;

    const float* __restrict__ Qg = qkv + ((size_t)(3 * g + 0) * BATCH + b) * ND;
    const float* __restrict__ Kg = qkv + ((size_t)(3 * g + 1) * BATCH + b) * ND;
    const float* __restrict__ Vg = qkv + ((size_t)(3 * g + 2) * BATCH + b) * ND;

    for (int e = t; e < 8192; e += 256) {
        const int i = e >> 6, k = e & 63;
        Ql[i * 65 + k] = Qg[e];
        Kl[i * 65 + k] = Kg[e];
    }
    __syncthreads();

    // scores: 8x8 register tile per thread
    {
        const int i0 = (t >> 4) * 8;
        const int j0 = (t & 15) * 8;
        float s[8][8];
        #pragma unroll
        for (int rr = 0; rr < 8; ++rr)
            #pragma unroll
            for (int cc = 0; cc < 8; ++cc) s[rr][cc] = 0.f;
        for (int k = 0; k < 64; ++k) {
            float qv[8], kv[8];
            #pragma unroll
            for (int rr = 0; rr < 8; ++rr) qv[rr] = Ql[(i0 + rr) * 65 + k];
            #pragma unroll
            for (int cc = 0; cc < 8; ++cc) kv[cc] = Kl[(j0 + cc) * 65 + k];
            #pragma unroll
            for (int rr = 0; rr < 8; ++rr)
                #pragma unroll
                for (int cc = 0; cc < 8; ++cc)
                    s[rr][cc] = fmaf(qv[rr], kv[cc], s[rr][cc]);
        }
        #pragma unroll
        for (int rr = 0; rr < 8; ++rr)
            #pragma unroll
            for (int cc = 0; cc < 8; ++cc)
                Sc[(i0 + rr) * 129 + (j0 + cc)] = s[rr][cc];
    }
    __syncthreads();

    // V fill (Q dead) + per-column partial max; column j, half h
    const int j = t & 127, h = t >> 7;
    {
        for (int e = t; e < 8192; e += 256) {
            const int i = e >> 6, k = e & 63;
            Ql[i * 65 + k] = Vg[e];
        }
        float m = -3.0e38f;
        for (int i = h * 64; i < h * 64 + 64; ++i)
            m = fmaxf(m, Sc[i * 129 + j]);
        Pm[h * 128 + j] = m;
    }
    __syncthreads();
    {
        const float m = fmaxf(Pm[j], Pm[128 + j]);
        float sum = 0.f;
        for (int i = h * 64; i < h * 64 + 64; ++i) {
            const float e = __expf(Sc[i * 129 + j] - m);
            Sc[i * 129 + j] = e;
            sum += e;
        }
        Ps[h * 128 + j] = sum;
    }
    __syncthreads();
    if (t < 128) Rden[t] = 1.0f / (Ps[t] + Ps[128 + t]);
    __syncthreads();

    // PV: 8 rows x 4 cols per thread
    {
        const int i0 = (t >> 4) * 8;
        const int k0 = (t & 15) * 4;
        float z[8][4];
        #pragma unroll
        for (int rr = 0; rr < 8; ++rr)
            #pragma unroll
            for (int cc = 0; cc < 4; ++cc) z[rr][cc] = 0.f;
        for (int jj = 0; jj < 128; ++jj) {
            const float rd = Rden[jj];
            float av[8], vv[4];
            #pragma unroll
            for (int rr = 0; rr < 8; ++rr) av[rr] = Sc[(i0 + rr) * 129 + jj] * rd;
            #pragma unroll
            for (int cc = 0; cc < 4; ++cc) vv[cc] = Ql[jj * 65 + k0 + cc];
            #pragma unroll
            for (int rr = 0; rr < 8; ++rr)
                #pragma unroll
                for (int cc = 0; cc < 4; ++cc)
                    z[rr][cc] = fmaf(av[rr], vv[cc], z[rr][cc]);
        }
        float* op = out + (size_t)b * (SEQ * QKVD) + (size_t)(g * 128) * QKVD + k0;
        #pragma unroll
        for (int rr = 0; rr < 8; ++rr) {
            float4 o;
            o.x = z[rr][0] * 0.125f; o.y = z[rr][1] * 0.125f;
            o.z = z[rr][2] * 0.125f; o.w = z[rr][3] * 0.125f;
            *reinterpret_cast<float4*>(op + (size_t)(i0 + rr) * QKVD) = o;
        }
    }
}

// ---------------- launcher --------------------------------------------------
extern "C" void kernel_launch(void* const* d_in, const int* in_sizes, int n_in,
                              void* d_out, int out_size, void* d_ws, size_t ws_size,
                              hipStream_t stream) {
    const float* x = (const float*)d_in[0];
    WArgs wa;
    for (int g = 0; g < 2; ++g)
        for (int q = 0; q < 3; ++q) {
            wa.W[g * 3 + q] = (const float*)d_in[1 + g * 6 + q * 2];
            wa.b[g * 3 + q] = (const float*)d_in[2 + g * 6 + q * 2];
        }

    short* xb  = (short*)d_ws;                                      // 2 MiB
    float* qkv = (float*)((char*)d_ws + (size_t)4 * 1024 * 1024);   // 12.6 MiB

    cvt_x_kernel<<<dim3(1024), dim3(256), 0, stream>>>(x, xb);
    qkv_gemm_kernel<<<dim3(768), dim3(256), 0, stream>>>(xb, wa, qkv);
    attn_kernel<<<dim3(BATCH, 2), dim3(256), 0, stream>>>(qkv, (float*)d_out);
}

// Round 14
// 344.530 us; speedup vs baseline: 1.5251x; 1.5251x over previous
//
#include <hip/hip_runtime.h>
#include <hip/hip_bf16.h>

#define BATCH 64
#define SEQ   256
#define EMB   64
#define QKVD  64
#define KD    8192      // L*EMB
#define ND    8192      // L*QKV
#define SEQD  16384     // SEQ*EMB (per-batch x row)
#define BKT   256       // k per tile: W row chunk = 1KB contiguous
#define NTK   (KD / BKT)   // 32 k-tiles

typedef __attribute__((ext_vector_type(8))) short bf16x8;
typedef __attribute__((ext_vector_type(4))) float f32x4;

struct WArgs { const float* W[6]; const float* b[6]; };

// branchless round-to-nearest-even fp32 -> bf16 bits (inputs are finite)
__device__ __forceinline__ short f2bf(float f) {
    unsigned u = __builtin_bit_cast(unsigned, f);
    u += 0x7fffu + ((u >> 16) & 1u);
    return (short)(u >> 16);
}

// async global->LDS, 16B per lane; LDS dest = wave-uniform base + lane*16
__device__ __forceinline__ void gl16(const void* g, void* l) {
    __builtin_amdgcn_global_load_lds(
        (const __attribute__((address_space(1))) void*)g,
        (__attribute__((address_space(3))) void*)l, 16, 0, 0);
}

__device__ __forceinline__ void barrier_fenced() {
    asm volatile("" ::: "memory");
    __builtin_amdgcn_s_barrier();
    asm volatile("" ::: "memory");
}

// ---------------- kernel 1: x fp32 -> bf16 ----------------------------------
__global__ __launch_bounds__(256)
void cvt_x_kernel(const float* __restrict__ x, short* __restrict__ xb) {
    const int i = (blockIdx.x * 256 + threadIdx.x) * 4;
    float4 v = *reinterpret_cast<const float4*>(x + i);
    short4 o;
    o.x = f2bf(v.x); o.y = f2bf(v.y); o.z = f2bf(v.z); o.w = f2bf(v.w);
    *reinterpret_cast<short4*>(xb + i) = o;
}

// ---------------- kernel 2: QKV projections ---------------------------------
// C[m][n] = sum_k xs[m,k] * W[n,k] + b[n], per gi in [0,6)
// 1 block/CU (160KB LDS), 4 waves, persistent over 3 n-tiles (6MB sequential W
// stream per block). BK=256: every W gl_lds issue = 1KB contiguous (DRAM
// row-buffer efficient). W double-buffered (2x64KB), A single-buffered (32KB).
// Counted vmcnt(16): W(t+1)'s 64KB stays in flight across compute(t).
// [r9 best-measured configuration: 345us total, ~4.8 TB/s real W stream]
__global__ __launch_bounds__(256, 1)
void qkv_gemm_kernel(const short* __restrict__ xb, WArgs wa,
                     float* __restrict__ qkv) {
    __shared__ __attribute__((aligned(16))) float W_lds[2][64 * BKT]; // 128KB
    __shared__ __attribute__((aligned(16))) short A_lds[64 * BKT];    // 32KB

    const int wv = threadIdx.x >> 6;
    const int ln = threadIdx.x & 63;
    const int r  = ln & 15;           // n within wave tile / A row in frag
    const int kb = ln >> 4;           // k sub-block of 8 within 32
    const int key = r & 7;

    for (int nt = 0; nt < 3; ++nt) {
        const int logical = blockIdx.x * 3 + nt;
        const int gi = logical >> 7;               // 0..5
        const int n0 = (logical & 127) * 64;       // n-tile origin
        const int g  = gi / 3;

        const char*  __restrict__ Wb8 =
            (const char*)(wa.W[gi] + (size_t)(n0 + wv * 16) * KD);
        const short* __restrict__ Ag = xb + g * KD;

        f32x4 acc0 = {0.f, 0.f, 0.f, 0.f};
        f32x4 acc1 = acc0, acc2 = acc0, acc3 = acc0;

        auto stageW = [&](int t, int slot) {       // 16 issues = 16KB/wave
            const char* tb = Wb8 + (size_t)t * 1024;
            #pragma unroll
            for (int i = 0; i < 16; ++i) {         // 1 issue = 1KB contiguous
                gl16(tb + (size_t)i * (KD * 4) + ((ln ^ (i & 7)) << 4),
                     (char*)&W_lds[slot][0] + (wv * 16 + i) * 1024);
            }
        };
        auto stageA = [&](int t) {                 // 8 issues/wave, coop 64 rows
            #pragma unroll
            for (int j = 0; j < 8; ++j) {
                const int jj  = wv * 8 + j;        // issue covers rows 2jj,2jj+1
                const int row = 2 * jj + (ln >> 5);
                const int c   = (ln & 31) ^ (row & 7);
                gl16((const char*)(Ag + (size_t)row * SEQD) + (size_t)t * 512 + (c << 4),
                     (char*)&A_lds[0] + jj * 1024);
            }
        };

        auto compute = [&](int slot) {
            const float* Wrow = &W_lds[slot][0] + (wv * 16 + r) * BKT;
            const char*  Ab   = (const char*)&A_lds[0];
            #pragma unroll
            for (int s = 0; s < 8; ++s) {
                const int cg = s * 8 + kb * 2;
                f32x4 w0 = *(const f32x4*)(Wrow + (((cg)     ^ key) << 2));
                f32x4 w1 = *(const f32x4*)(Wrow + (((cg + 1) ^ key) << 2));
                bf16x8 bb;
                bb[0] = f2bf(w0[0]); bb[1] = f2bf(w0[1]);
                bb[2] = f2bf(w0[2]); bb[3] = f2bf(w0[3]);
                bb[4] = f2bf(w1[0]); bb[5] = f2bf(w1[1]);
                bb[6] = f2bf(w1[2]); bb[7] = f2bf(w1[3]);
                const int ca = (s * 4 + kb) ^ key;  // A 16B-chunk (swizzled)
                const bf16x8 a0 = *(const bf16x8*)(Ab + (r)      * 512 + (ca << 4));
                const bf16x8 a1 = *(const bf16x8*)(Ab + (r + 16) * 512 + (ca << 4));
                const bf16x8 a2 = *(const bf16x8*)(Ab + (r + 32) * 512 + (ca << 4));
                const bf16x8 a3 = *(const bf16x8*)(Ab + (r + 48) * 512 + (ca << 4));
                acc0 = __builtin_amdgcn_mfma_f32_16x16x32_bf16(a0, bb, acc0, 0, 0, 0);
                acc1 = __builtin_amdgcn_mfma_f32_16x16x32_bf16(a1, bb, acc1, 0, 0, 0);
                acc2 = __builtin_amdgcn_mfma_f32_16x16x32_bf16(a2, bb, acc2, 0, 0, 0);
                acc3 = __builtin_amdgcn_mfma_f32_16x16x32_bf16(a3, bb, acc3, 0, 0, 0);
            }
        };

        // prologue ledger order: W(0), A(0), W(1) -> vmcnt(16) at t=0 is exact
        stageW(0, 0);
        stageA(0);
        stageW(1, 1);

        for (int t = 0; t < NTK; ++t) {
            if (t < NTK - 2) { asm volatile("s_waitcnt vmcnt(16)" ::: "memory"); }
            else             { asm volatile("s_waitcnt vmcnt(0)"  ::: "memory"); }
            __builtin_amdgcn_sched_barrier(0);
            barrier_fenced();            // all waves' tile-t stages in LDS
            compute(t & 1);
            barrier_fenced();            // WAR: A buf + W slot free
            if (t + 1 < NTK) stageA(t + 1);
            if (t + 2 < NTK) stageW(t + 2, t & 1);
        }
        barrier_fenced();

        // D layout (m89): col = lane&15, row = (lane>>4)*4 + reg
        const int nbr = n0 + wv * 16 + r;
        const float bias = wa.b[gi][nbr];
        float* orow = qkv + (size_t)gi * (BATCH * ND) + nbr;
        #pragma unroll
        for (int reg = 0; reg < 4; ++reg) {
            const int m = kb * 4 + reg;
            orow[(size_t)(m)      * ND] = acc0[reg] + bias;
            orow[(size_t)(m + 16) * ND] = acc1[reg] + bias;
            orow[(size_t)(m + 32) * ND] = acc2[reg] + bias;
            orow[(size_t)(m + 48) * ND] = acc3[reg] + bias;
        }
    }
}

// ---------------- kernel 3: attention per (batch, group) -------------------
// scores[i][j] = Q[i,:]·K[j,:]; softmax over i (query axis); Z = attn·V; ×0.125
__global__ __launch_bounds__(256)
void attn_kernel(const float* __restrict__ qkv, float* __restrict__ out) {
    __shared__ float Ql[128 * 65];   // Q, then reused for V
    __shared__ float Kl[128 * 65];
    __shared__ float Sc[128 * 129];
    __shared__ float Pm[256];
    __shared__ float Ps[256];
    __shared__ float Rden[128];

    const int b = blockIdx.x;
    const int g = blockIdx.y;
    const int t = threadIdx.x;

    const float* __restrict__ Qg = qkv + ((size_t)(3 * g + 0) * BATCH + b) * ND;
    const float* __restrict__ Kg = qkv + ((size_t)(3 * g + 1) * BATCH + b) * ND;
    const float* __restrict__ Vg = qkv + ((size_t)(3 * g + 2) * BATCH + b) * ND;

    for (int e = t; e < 8192; e += 256) {
        const int i = e >> 6, k = e & 63;
        Ql[i * 65 + k] = Qg[e];
        Kl[i * 65 + k] = Kg[e];
    }
    __syncthreads();

    // scores: 8x8 register tile per thread
    {
        const int i0 = (t >> 4) * 8;
        const int j0 = (t & 15) * 8;
        float s[8][8];
        #pragma unroll
        for (int rr = 0; rr < 8; ++rr)
            #pragma unroll
            for (int cc = 0; cc < 8; ++cc) s[rr][cc] = 0.f;
        for (int k = 0; k < 64; ++k) {
            float qv[8], kv[8];
            #pragma unroll
            for (int rr = 0; rr < 8; ++rr) qv[rr] = Ql[(i0 + rr) * 65 + k];
            #pragma unroll
            for (int cc = 0; cc < 8; ++cc) kv[cc] = Kl[(j0 + cc) * 65 + k];
            #pragma unroll
            for (int rr = 0; rr < 8; ++rr)
                #pragma unroll
                for (int cc = 0; cc < 8; ++cc)
                    s[rr][cc] = fmaf(qv[rr], kv[cc], s[rr][cc]);
        }
        #pragma unroll
        for (int rr = 0; rr < 8; ++rr)
            #pragma unroll
            for (int cc = 0; cc < 8; ++cc)
                Sc[(i0 + rr) * 129 + (j0 + cc)] = s[rr][cc];
    }
    __syncthreads();

    // V fill (Q dead) + per-column partial max; column j, half h
    const int j = t & 127, h = t >> 7;
    {
        for (int e = t; e < 8192; e += 256) {
            const int i = e >> 6, k = e & 63;
            Ql[i * 65 + k] = Vg[e];
        }
        float m = -3.0e38f;
        for (int i = h * 64; i < h * 64 + 64; ++i)
            m = fmaxf(m, Sc[i * 129 + j]);
        Pm[h * 128 + j] = m;
    }
    __syncthreads();
    {
        const float m = fmaxf(Pm[j], Pm[128 + j]);
        float sum = 0.f;
        for (int i = h * 64; i < h * 64 + 64; ++i) {
            const float e = __expf(Sc[i * 129 + j] - m);
            Sc[i * 129 + j] = e;
            sum += e;
        }
        Ps[h * 128 + j] = sum;
    }
    __syncthreads();
    if (t < 128) Rden[t] = 1.0f / (Ps[t] + Ps[128 + t]);
    __syncthreads();

    // PV: 8 rows x 4 cols per thread
    {
        const int i0 = (t >> 4) * 8;
        const int k0 = (t & 15) * 4;
        float z[8][4];
        #pragma unroll
        for (int rr = 0; rr < 8; ++rr)
            #pragma unroll
            for (int cc = 0; cc < 4; ++cc) z[rr][cc] = 0.f;
        for (int jj = 0; jj < 128; ++jj) {
            const float rd = Rden[jj];
            float av[8], vv[4];
            #pragma unroll
            for (int rr = 0; rr < 8; ++rr) av[rr] = Sc[(i0 + rr) * 129 + jj] * rd;
            #pragma unroll
            for (int cc = 0; cc < 4; ++cc) vv[cc] = Ql[jj * 65 + k0 + cc];
            #pragma unroll
            for (int rr = 0; rr < 8; ++rr)
                #pragma unroll
                for (int cc = 0; cc < 4; ++cc)
                    z[rr][cc] = fmaf(av[rr], vv[cc], z[rr][cc]);
        }
        float* op = out + (size_t)b * (SEQ * QKVD) + (size_t)(g * 128) * QKVD + k0;
        #pragma unroll
        for (int rr = 0; rr < 8; ++rr) {
            float4 o;
            o.x = z[rr][0] * 0.125f; o.y = z[rr][1] * 0.125f;
            o.z = z[rr][2] * 0.125f; o.w = z[rr][3] * 0.125f;
            *reinterpret_cast<float4*>(op + (size_t)(i0 + rr) * QKVD) = o;
        }
    }
}

// ---------------- launcher --------------------------------------------------
extern "C" void kernel_launch(void* const* d_in, const int* in_sizes, int n_in,
                              void* d_out, int out_size, void* d_ws, size_t ws_size,
                              hipStream_t stream) {
    const float* x = (const float*)d_in[0];
    WArgs wa;
    for (int g = 0; g < 2; ++g)
        for (int q = 0; q < 3; ++q) {
            wa.W[g * 3 + q] = (const float*)d_in[1 + g * 6 + q * 2];
            wa.b[g * 3 + q] = (const float*)d_in[2 + g * 6 + q * 2];
        }

    short* xb  = (short*)d_ws;                                      // 2 MiB
    float* qkv = (float*)((char*)d_ws + (size_t)4 * 1024 * 1024);   // 12.6 MiB

    cvt_x_kernel<<<dim3(1024), dim3(256), 0, stream>>>(x, xb);
    qkv_gemm_kernel<<<dim3(256), dim3(256), 0, stream>>>(xb, wa, qkv);
    attn_kernel<<<dim3(BATCH, 2), dim3(256), 0, stream>>>(qkv, (float*)d_out);
}